// Round 4
// baseline (609.206 us; speedup 1.0000x reference)
//
#include <hip/hip_runtime.h>
#include <math.h>

#define Bsz 256
#define T   512
#define Dd  8
#define Hh  120
#define Ll  4
#define NHn 8
#define HDd 15
#define HP  20      // padded head row stride: bank-conflict-free (n*20 % 32 all distinct)
#define EPSf 1e-5f

typedef float v2f __attribute__((ext_vector_type(2)));

__device__ __forceinline__ float fast_rcp(float x) {
#if __has_builtin(__builtin_amdgcn_rcpf)
    return __builtin_amdgcn_rcpf(x);
#else
    return 1.f / x;
#endif
}
__device__ __forceinline__ float tanh_fast(float x) {
    float e = __expf(2.f * x);
    return 1.f - 2.f * fast_rcp(e + 1.f);
}
__device__ __forceinline__ float sigm_fast(float x) {
    return fast_rcp(1.f + __expf(-x));
}
__device__ __forceinline__ v2f fma2(v2f a, v2f b, v2f c) {
#if __has_builtin(__builtin_elementwise_fma)
    return __builtin_elementwise_fma(a, b, c);
#else
    v2f r; r[0] = fmaf(a[0], b[0], c[0]); r[1] = fmaf(a[1], b[1], c[1]); return r;
#endif
}

// Block = 1024 threads = 4 layer-groups of 256 (4 waves each).
// Within a group: unit u (0..119) is handled by lane pair (2u, 2u+1):
//   even lane -> gates i,f ; odd lane -> gates z,o ; one shfl_xor(1) exchange.
// Pipeline skew (proven in R3): layer l computes gates for t_g = tau - 2l and
// (on wave 0 of the group) the projection of t_p = t_g - 1 in the same tick.
// Parity of t_g vs t_p guarantees no xs read/write collision -> 1 barrier/tick.
__global__ __launch_bounds__(1024, 4) void slstm_kernel(
    const float* __restrict__ x,
    const float* __restrict__ Wi, const float* __restrict__ Wf,
    const float* __restrict__ Wz, const float* __restrict__ Wo,
    const float* __restrict__ Ri, const float* __restrict__ Rf,
    const float* __restrict__ Rz, const float* __restrict__ Ro,
    const float* __restrict__ bi, const float* __restrict__ bf,
    const float* __restrict__ bz, const float* __restrict__ bo,
    const float* __restrict__ Wp, const float* __restrict__ bp,
    float* __restrict__ last_out)   // [Bsz][Dd]
{
    __shared__ __align__(16) float xs[T * Dd];            // 16 KB residual stream
    __shared__ __align__(16) float hb[Ll][2][NHn * HP];   // 5 KB, padded heads

    const int tid = threadIdx.x;
    const int b   = blockIdx.x;
    const int l   = tid >> 8;    // layer group 0..3
    const int j   = tid & 255;   // lane within group
    const int sub = j & 1;       // 0: i,f   1: z,o
    const bool gl = (j < 2 * Hh);
    const int u   = gl ? (j >> 1) : (Hh - 1);   // unit 0..119 (clamped)
    const int n   = u / HDd;
    const int e   = u - n * HDd;

    // ---- prologue: stage x (float4), zero h ----
    {
        const float4* xg = (const float4*)(x + (size_t)b * T * Dd);
        ((float4*)xs)[tid] = xg[tid];               // T*Dd/4 = 1024
        float* hbf = (float*)hb;                    // 1280 floats
        hbf[tid < 1280 ? tid : 1279] = 0.f;
        if (tid < 1280 - 1024) hbf[1024 + tid] = 0.f;
    }

    // ---- per-lane weights for 2 gates -> registers (46 floats) ----
    const float* Wa = sub ? Wz : Wi;
    const float* Wb = sub ? Wo : Wf;
    const float* Ra = sub ? Rz : Ri;
    const float* Rb = sub ? Ro : Rf;
    const float* ba = sub ? bz : bi;
    const float* bb = sub ? bo : bf;

    v2f w2[Dd], r2[HDd], bias2;
    {
        const int row = (l * Hh + u) * Dd;
#pragma unroll
        for (int d = 0; d < Dd; ++d) { w2[d][0] = Wa[row + d]; w2[d][1] = Wb[row + d]; }
        const int rb = ((l * NHn + n) * HDd) * HDd + e;
#pragma unroll
        for (int k = 0; k < HDd; ++k) { r2[k][0] = Ra[rb + k * HDd]; r2[k][1] = Rb[rb + k * HDd]; }
        bias2[0] = ba[l * Hh + u]; bias2[1] = bb[l * Hh + u];
    }

    // ---- projection weights (used by wave 0 of the group; loaded clamped) ----
    const int p  = j & 63;
    const int d8 = p & 7, ch = p >> 3;
    float wp_r[HDd], bp_r;
    {
        const int base = l * Dd * Hh + d8 * Hh + ch * HDd;
#pragma unroll
        for (int k = 0; k < HDd; ++k) wp_r[k] = Wp[base + k];
        bp_r = bp[l * Dd + d8];
    }

    float cst = 0.f, nst = 0.f, mst = 0.f;

    __syncthreads();

    // ---- pipelined recurrence: ONE barrier per tick ----
    for (int tau = 0; tau < T + 2 * Ll - 1; ++tau) {
        const int t_g = tau - 2 * l;       // gate timestep
        const int t_p = t_g - 1;           // projection timestep

        if (gl && (t_g >= 0) && (t_g < T)) {
            const float* hcur = hb[l][t_g & 1];
            const float4* xt4 = (const float4*)(xs + t_g * Dd);
            const float4 xa = xt4[0], xb2 = xt4[1];
            const float xv[Dd] = {xa.x, xa.y, xa.z, xa.w, xb2.x, xb2.y, xb2.z, xb2.w};
            const float4* h4 = (const float4*)(hcur + n * HP);
            const float4 h0 = h4[0], h1 = h4[1], h2 = h4[2], h3 = h4[3];
            const float hv[16] = {h0.x, h0.y, h0.z, h0.w, h1.x, h1.y, h1.z, h1.w,
                                  h2.x, h2.y, h2.z, h2.w, h3.x, h3.y, h3.z, h3.w};
            v2f g2 = bias2;
#pragma unroll
            for (int d = 0; d < Dd; ++d)  g2 = fma2((v2f){xv[d], xv[d]}, w2[d], g2);
#pragma unroll
            for (int k = 0; k < HDd; ++k) g2 = fma2((v2f){hv[k], hv[k]}, r2[k], g2);

            float zv = 0.f, ov = 0.f;
            if (sub) { zv = tanh_fast(g2[0]); ov = sigm_fast(g2[1]); }
            const float zr = __shfl_xor(zv, 1);
            const float orr = __shfl_xor(ov, 1);
            if (!sub) {
                const float it = g2[0], ft = g2[1];
                const float mn = fmaxf(ft + mst, it);
                const float ip = __expf(it - mn);
                const float fp = __expf(ft + mst - mn);
                cst = fmaf(fp, cst, ip * zr);
                nst = fmaf(fp, nst, ip);
                mst = mn;
                hb[l][(t_g & 1) ^ 1][n * HP + e] = orr * cst * fast_rcp(nst);
            }
        }

        // projection of h(t_p) on wave 0 of the group, residual into xs[t_p]
        if ((j < 64) && (t_p >= 0) && (t_p < T)) {
            const float4* h4 = (const float4*)(hb[l][t_g & 1] + ch * HP);
            const float4 h0 = h4[0], h1 = h4[1], h2 = h4[2], h3 = h4[3];
            const float hv[16] = {h0.x, h0.y, h0.z, h0.w, h1.x, h1.y, h1.z, h1.w,
                                  h2.x, h2.y, h2.z, h2.w, h3.x, h3.y, h3.z, h3.w};
            float s = 0.f;
#pragma unroll
            for (int k = 0; k < HDd; ++k) s = fmaf(hv[k], wp_r[k], s);
            s += __shfl_xor(s, 8);
            s += __shfl_xor(s, 16);
            s += __shfl_xor(s, 32);
            if (p < Dd) xs[t_p * Dd + p] += s + bp_r;
        }

        __syncthreads();
    }

    if (tid < Dd) last_out[b * Dd + tid] = xs[(T - 1) * Dd + tid];
}

// One block of Bsz threads: batch-norm over batch + FC + sigmoid.
__global__ __launch_bounds__(Bsz) void bn_fc_kernel(
    const float* __restrict__ last,   // [Bsz][Dd]
    const float* __restrict__ gamma, const float* __restrict__ beta,
    const float* __restrict__ Wfc,   const float* __restrict__ bfc,
    float* __restrict__ out)          // [Bsz]
{
    __shared__ float ls[Bsz][Dd];
    __shared__ float mu[Dd], rstdg[Dd], bet[Dd], wfc[Dd];
    const int tid = threadIdx.x;
#pragma unroll
    for (int d = 0; d < Dd; ++d) ls[tid][d] = last[tid * Dd + d];
    __syncthreads();
    if (tid < Dd) {
        float s = 0.f;
        for (int bb = 0; bb < Bsz; ++bb) s += ls[bb][tid];
        const float mean = s * (1.f / Bsz);
        float v = 0.f;
        for (int bb = 0; bb < Bsz; ++bb) {
            const float dd = ls[bb][tid] - mean;
            v += dd * dd;
        }
        v *= (1.f / Bsz);
        mu[tid]    = mean;
        rstdg[tid] = rsqrtf(v + EPSf) * gamma[tid];
        bet[tid]   = beta[tid];
        wfc[tid]   = Wfc[tid];
    }
    __syncthreads();
    float acc = bfc[0];
#pragma unroll
    for (int d = 0; d < Dd; ++d)
        acc += ((ls[tid][d] - mu[d]) * rstdg[d] + bet[d]) * wfc[d];
    out[tid] = sigm_fast(acc);
}

extern "C" void kernel_launch(void* const* d_in, const int* in_sizes, int n_in,
                              void* d_out, int out_size, void* d_ws, size_t ws_size,
                              hipStream_t stream) {
    const float* x    = (const float*)d_in[0];
    const float* Wi   = (const float*)d_in[1];
    const float* Wf   = (const float*)d_in[2];
    const float* Wz   = (const float*)d_in[3];
    const float* Wo   = (const float*)d_in[4];
    const float* Ri   = (const float*)d_in[5];
    const float* Rf   = (const float*)d_in[6];
    const float* Rz   = (const float*)d_in[7];
    const float* Ro   = (const float*)d_in[8];
    const float* bi   = (const float*)d_in[9];
    const float* bf   = (const float*)d_in[10];
    const float* bz   = (const float*)d_in[11];
    const float* bo   = (const float*)d_in[12];
    const float* Wp   = (const float*)d_in[13];
    const float* bp   = (const float*)d_in[14];
    const float* gamma= (const float*)d_in[15];
    const float* beta = (const float*)d_in[16];
    const float* Wfc  = (const float*)d_in[17];
    const float* bfc  = (const float*)d_in[18];

    float* last_ws = (float*)d_ws;          // Bsz*Dd floats
    float* out     = (float*)d_out;         // Bsz floats

    slstm_kernel<<<Bsz, 1024, 0, stream>>>(x, Wi, Wf, Wz, Wo, Ri, Rf, Rz, Ro,
                                           bi, bf, bz, bo, Wp, bp, last_ws);
    bn_fc_kernel<<<1, Bsz, 0, stream>>>(last_ws, gamma, beta, Wfc, bfc, out);
}

// Round 5
// 467.261 us; speedup vs baseline: 1.3038x; 1.3038x over previous
//
#include <hip/hip_runtime.h>
#include <math.h>

#define Bsz 256
#define T   512
#define Dd  8
#define Hh  120
#define Ll  4
#define NHn 8
#define HDd 15
#define HP  20      // padded head row stride: banks (n*20)%32 all distinct -> conflict-free
#define EPSf 1e-5f

__device__ __forceinline__ float fast_rcp(float x) {
#if __has_builtin(__builtin_amdgcn_rcpf)
    return __builtin_amdgcn_rcpf(x);
#else
    return 1.f / x;
#endif
}
__device__ __forceinline__ float tanh_fast(float x) {
    float e = __expf(2.f * x);
    return 1.f - 2.f * fast_rcp(e + 1.f);
}
__device__ __forceinline__ float sigm_fast(float x) {
    return fast_rcp(1.f + __expf(-x));
}

// Block = 512 threads = 4 layer-groups of 128 (2 waves each).
// Pipeline skew (proven R3): layer l computes gates for t_g = tau - 2l and the
// projection of t_p = t_g - 1 on wave 1 of the group in the SAME tick; xs
// gate-reads (t_g) and proj-writes (t_p) differ in parity -> 1 barrier/tick.
__global__ __launch_bounds__(512, 2) void slstm_kernel(
    const float* __restrict__ x,
    const float* __restrict__ Wi, const float* __restrict__ Wf,
    const float* __restrict__ Wz, const float* __restrict__ Wo,
    const float* __restrict__ Ri, const float* __restrict__ Rf,
    const float* __restrict__ Rz, const float* __restrict__ Ro,
    const float* __restrict__ bi, const float* __restrict__ bf,
    const float* __restrict__ bz, const float* __restrict__ bo,
    const float* __restrict__ Wp, const float* __restrict__ bp,
    float* __restrict__ last_out)   // [Bsz][Dd]
{
    __shared__ __align__(16) float xs[T * Dd];            // 16 KB residual stream
    __shared__ __align__(16) float hb[Ll][2][NHn * HP];   // 5 KB, padded heads

    const int tid = threadIdx.x;
    const int b   = blockIdx.x;
    const int l   = tid >> 7;    // layer group 0..3
    const int j   = tid & 127;   // lane within group

    // ---- prologue: stage x (float4), zero h (incl. pads) ----
    {
        const float4* xg  = (const float4*)(x + (size_t)b * T * Dd);
        float4*       xs4 = (float4*)xs;
        xs4[tid]       = xg[tid];          // T*Dd/4 = 1024 = 2*512
        xs4[tid + 512] = xg[tid + 512];
        float* hbf = (float*)hb;           // Ll*2*NHn*HP = 1280 floats
        hbf[tid]       = 0.f;
        hbf[tid + 512] = 0.f;
        if (tid < 256) hbf[tid + 1024] = 0.f;
    }

    // ---- per-thread gate weights -> registers (unconditional, clamped) ----
    const bool gl = (j < Hh);
    const int jj  = gl ? j : 0;
    const int n   = jj / HDd;
    const int e   = jj - n * HDd;
    float wI[Dd], wF[Dd], wZ[Dd], wO[Dd];
    float rI[HDd], rF[HDd], rZ[HDd], rO[HDd];
    {
        const int row = (l * Hh + jj) * Dd;
#pragma unroll
        for (int d = 0; d < Dd; ++d) {
            wI[d] = Wi[row + d]; wF[d] = Wf[row + d];
            wZ[d] = Wz[row + d]; wO[d] = Wo[row + d];
        }
        const int rb = ((l * NHn + n) * HDd) * HDd + e;
#pragma unroll
        for (int d = 0; d < HDd; ++d) {
            rI[d] = Ri[rb + d * HDd]; rF[d] = Rf[rb + d * HDd];
            rZ[d] = Rz[rb + d * HDd]; rO[d] = Ro[rb + d * HDd];
        }
    }
    float bI = bi[l * Hh + jj], bF = bf[l * Hh + jj];
    float bZ = bz[l * Hh + jj], bO = bo[l * Hh + jj];

    // ---- projection weights (used by wave 1; loaded by all, clamped) ----
    const int p  = (j >= 64) ? (j - 64) : j;   // lane within wave 1
    const int d8 = p & 7, ch = p >> 3;
    float wp_r[16];
    {
        const int base = l * Dd * Hh + d8 * Hh + ch * HDd;
#pragma unroll
        for (int k = 0; k < HDd; ++k) wp_r[k] = Wp[base + k];
        wp_r[15] = 0.f;   // pairs with hb pad element (always 0)
    }
    float bp_r = bp[l * Dd + d8];

    float cst = 0.f, nst = 0.f, mst = 0.f;

    __syncthreads();

    // ---- pipelined recurrence: ONE barrier per tick ----
    for (int tau = 0; tau < T + 2 * Ll - 1; ++tau) {
        // IN-LOOP PIN: every weight is "redefined" by an opaque no-op asm each
        // iteration -> the allocator cannot fold them back to loads; they must
        // stay VGPR-resident across the whole loop.
#pragma unroll
        for (int d = 0; d < Dd; ++d)
            asm volatile("" : "+v"(wI[d]), "+v"(wF[d]), "+v"(wZ[d]), "+v"(wO[d]));
#pragma unroll
        for (int d = 0; d < HDd; ++d)
            asm volatile("" : "+v"(rI[d]), "+v"(rF[d]), "+v"(rZ[d]), "+v"(rO[d]));
#pragma unroll
        for (int k = 0; k < 16; k += 4)
            asm volatile("" : "+v"(wp_r[k]), "+v"(wp_r[k+1]), "+v"(wp_r[k+2]), "+v"(wp_r[k+3]));
        asm volatile("" : "+v"(bI), "+v"(bF), "+v"(bZ), "+v"(bO), "+v"(bp_r));

        const int t_g = tau - 2 * l;       // gate timestep
        const int t_p = t_g - 1;           // projection timestep

        // gates: read xs[t_g] + h(t_g-1), write h(t_g)
        if (gl && (t_g >= 0) && (t_g < T)) {
            const float4* xt4 = (const float4*)(xs + t_g * Dd);
            const float4 xa = xt4[0], xb2 = xt4[1];
            const float xv[Dd] = {xa.x, xa.y, xa.z, xa.w, xb2.x, xb2.y, xb2.z, xb2.w};
            float gi = bI, gf = bF, gz = bZ, go = bO;
#pragma unroll
            for (int d = 0; d < Dd; ++d) {
                gi = fmaf(xv[d], wI[d], gi);
                gf = fmaf(xv[d], wF[d], gf);
                gz = fmaf(xv[d], wZ[d], gz);
                go = fmaf(xv[d], wO[d], go);
            }
            const float4* h4 = (const float4*)(&hb[l][t_g & 1][n * HP]);
            const float4 h0 = h4[0], h1 = h4[1], h2 = h4[2], h3 = h4[3];
            const float hv[16] = {h0.x, h0.y, h0.z, h0.w, h1.x, h1.y, h1.z, h1.w,
                                  h2.x, h2.y, h2.z, h2.w, h3.x, h3.y, h3.z, h3.w};
#pragma unroll
            for (int d = 0; d < HDd; ++d) {
                gi = fmaf(hv[d], rI[d], gi);
                gf = fmaf(hv[d], rF[d], gf);
                gz = fmaf(hv[d], rZ[d], gz);
                go = fmaf(hv[d], rO[d], go);
            }
            const float z  = tanh_fast(gz);
            const float o  = sigm_fast(go);
            const float mn = fmaxf(gf + mst, gi);
            const float ip = __expf(gi - mn);
            const float fp = __expf(gf + mst - mn);
            cst = fmaf(fp, cst, ip * z);
            nst = fmaf(fp, nst, ip);
            mst = mn;
            hb[l][(t_g & 1) ^ 1][n * HP + e] = o * cst * fast_rcp(nst);
        }

        // projection of h(t_p) (wave 1 of the group), residual into xs[t_p]
        if ((j >= 64) && (t_p >= 0) && (t_p < T)) {
            // h(t_p) lives in buffer (t_p&1)^1 == t_g&1
            const float4* h4 = (const float4*)(&hb[l][t_g & 1][ch * HP]);
            const float4 h0 = h4[0], h1 = h4[1], h2 = h4[2], h3 = h4[3];
            const float hv[16] = {h0.x, h0.y, h0.z, h0.w, h1.x, h1.y, h1.z, h1.w,
                                  h2.x, h2.y, h2.z, h2.w, h3.x, h3.y, h3.z, h3.w};
            float s = 0.f;
#pragma unroll
            for (int k = 0; k < 16; ++k) s = fmaf(hv[k], wp_r[k], s);
            s += __shfl_xor(s, 8);
            s += __shfl_xor(s, 16);
            s += __shfl_xor(s, 32);
            if (p < Dd) xs[t_p * Dd + p] += s + bp_r;   // residual update
        }

        __syncthreads();
    }

    if (tid < Dd) last_out[b * Dd + tid] = xs[(T - 1) * Dd + tid];
}

// One block of Bsz threads: batch-norm over batch + FC + sigmoid.
// Mean/var parallelized: 32 groups x 8 dims partials, then 8-lane combine.
__global__ __launch_bounds__(Bsz) void bn_fc_kernel(
    const float* __restrict__ last,   // [Bsz][Dd]
    const float* __restrict__ gamma, const float* __restrict__ beta,
    const float* __restrict__ Wfc,   const float* __restrict__ bfc,
    float* __restrict__ out)          // [Bsz]
{
    __shared__ __align__(16) float ls[Bsz][Dd];
    __shared__ float rsum[32][Dd], rsq[32][Dd];
    __shared__ float mu[Dd], rstdg[Dd], bet[Dd], wfc[Dd];
    const int tid = threadIdx.x;
    {
        const float4* lg = (const float4*)last;
        ((float4*)ls)[tid]       = lg[tid];        // 256*8 floats = 512 float4
        ((float4*)ls)[tid + 256] = lg[tid + 256];
    }
    __syncthreads();
    {
        const int d = tid & 7, g = tid >> 3;       // 32 groups x 8 dims
        float s = 0.f, q = 0.f;
#pragma unroll
        for (int k = 0; k < 8; ++k) {
            const float v = ls[g + 32 * k][d];
            s += v; q = fmaf(v, v, q);
        }
        rsum[g][d] = s; rsq[g][d] = q;
    }
    __syncthreads();
    if (tid < Dd) {
        float s = 0.f, q = 0.f;
#pragma unroll
        for (int g = 0; g < 32; ++g) { s += rsum[g][tid]; q += rsq[g][tid]; }
        const float mean = s * (1.f / Bsz);
        const float var  = q * (1.f / Bsz) - mean * mean;
        mu[tid]    = mean;
        rstdg[tid] = rsqrtf(fmaxf(var, 0.f) + EPSf) * gamma[tid];
        bet[tid]   = beta[tid];
        wfc[tid]   = Wfc[tid];
    }
    __syncthreads();
    float acc = bfc[0];
#pragma unroll
    for (int d = 0; d < Dd; ++d)
        acc += ((ls[tid][d] - mu[d]) * rstdg[d] + bet[d]) * wfc[d];
    out[tid] = sigm_fast(acc);
}

extern "C" void kernel_launch(void* const* d_in, const int* in_sizes, int n_in,
                              void* d_out, int out_size, void* d_ws, size_t ws_size,
                              hipStream_t stream) {
    const float* x    = (const float*)d_in[0];
    const float* Wi   = (const float*)d_in[1];
    const float* Wf   = (const float*)d_in[2];
    const float* Wz   = (const float*)d_in[3];
    const float* Wo   = (const float*)d_in[4];
    const float* Ri   = (const float*)d_in[5];
    const float* Rf   = (const float*)d_in[6];
    const float* Rz   = (const float*)d_in[7];
    const float* Ro   = (const float*)d_in[8];
    const float* bi   = (const float*)d_in[9];
    const float* bf   = (const float*)d_in[10];
    const float* bz   = (const float*)d_in[11];
    const float* bo   = (const float*)d_in[12];
    const float* Wp   = (const float*)d_in[13];
    const float* bp   = (const float*)d_in[14];
    const float* gamma= (const float*)d_in[15];
    const float* beta = (const float*)d_in[16];
    const float* Wfc  = (const float*)d_in[17];
    const float* bfc  = (const float*)d_in[18];

    float* last_ws = (float*)d_ws;          // Bsz*Dd floats
    float* out     = (float*)d_out;         // Bsz floats

    slstm_kernel<<<Bsz, 512, 0, stream>>>(x, Wi, Wf, Wz, Wo, Ri, Rf, Rz, Ro,
                                          bi, bf, bz, bo, Wp, bp, last_ws);
    bn_fc_kernel<<<1, Bsz, 0, stream>>>(last_ws, gamma, beta, Wfc, bfc, out);
}

// Round 6
// 466.365 us; speedup vs baseline: 1.3063x; 1.0019x over previous
//
#include <hip/hip_runtime.h>
#include <math.h>

#define Bsz 256
#define T   512
#define Dd  8
#define Hh  120
#define Ll  4
#define NHn 8
#define HDd 15
#define HP  20      // padded head row stride: banks (n*20)%32 all distinct -> conflict-free
#define EPSf 1e-5f

__device__ __forceinline__ float fast_rcp(float x) {
#if __has_builtin(__builtin_amdgcn_rcpf)
    return __builtin_amdgcn_rcpf(x);
#else
    return 1.f / x;
#endif
}
__device__ __forceinline__ float tanh_fast(float x) {
    float e = __expf(2.f * x);
    return 1.f - 2.f * fast_rcp(e + 1.f);
}
__device__ __forceinline__ float sigm_fast(float x) {
    return fast_rcp(1.f + __expf(-x));
}

// Block = 512 threads = 4 layer-groups of 128 (2 waves each).
// Pipeline skew (proven R3): layer l computes gates for t_g = tau - 2l and the
// projection of t_p = t_g - 1 on wave 1 of the group in the SAME tick; xs
// gate-reads (t_g) and proj-writes (t_p) differ in parity -> 1 barrier/tick.
// amdgpu_waves_per_eu(2,2): cap occupancy target at 2 waves/SIMD so the RA
// gets a 256-VGPR budget and keeps all ~110 weight floats register-resident
// (launch_bounds(512,2) alone only sets the MIN -> RA targeted ~7 waves/SIMD
// and re-loaded weights from cache every tick).
__global__
__attribute__((amdgpu_flat_work_group_size(512, 512)))
__attribute__((amdgpu_waves_per_eu(2, 2)))
void slstm_kernel(
    const float* __restrict__ x,
    const float* __restrict__ Wi, const float* __restrict__ Wf,
    const float* __restrict__ Wz, const float* __restrict__ Wo,
    const float* __restrict__ Ri, const float* __restrict__ Rf,
    const float* __restrict__ Rz, const float* __restrict__ Ro,
    const float* __restrict__ bi, const float* __restrict__ bf,
    const float* __restrict__ bz, const float* __restrict__ bo,
    const float* __restrict__ Wp, const float* __restrict__ bp,
    float* __restrict__ last_out)   // [Bsz][Dd]
{
    __shared__ __align__(16) float xs[T * Dd];            // 16 KB residual stream
    __shared__ __align__(16) float hb[Ll][2][NHn * HP];   // 5 KB, padded heads

    const int tid = threadIdx.x;
    const int b   = blockIdx.x;
    const int l   = tid >> 7;    // layer group 0..3
    const int j   = tid & 127;   // lane within group

    // ---- prologue: stage x (float4), zero h (incl. pads) ----
    {
        const float4* xg  = (const float4*)(x + (size_t)b * T * Dd);
        float4*       xs4 = (float4*)xs;
        xs4[tid]       = xg[tid];          // T*Dd/4 = 1024 = 2*512
        xs4[tid + 512] = xg[tid + 512];
        float* hbf = (float*)hb;           // Ll*2*NHn*HP = 1280 floats
        hbf[tid]       = 0.f;
        hbf[tid + 512] = 0.f;
        if (tid < 256) hbf[tid + 1024] = 0.f;
    }

    // ---- per-thread gate weights -> registers (unconditional, clamped) ----
    const bool gl = (j < Hh);
    const int jj  = gl ? j : 0;
    const int n   = jj / HDd;
    const int e   = jj - n * HDd;
    float wI[Dd], wF[Dd], wZ[Dd], wO[Dd];
    float rI[HDd], rF[HDd], rZ[HDd], rO[HDd];
    {
        const int row = (l * Hh + jj) * Dd;
#pragma unroll
        for (int d = 0; d < Dd; ++d) {
            wI[d] = Wi[row + d]; wF[d] = Wf[row + d];
            wZ[d] = Wz[row + d]; wO[d] = Wo[row + d];
        }
        const int rb = ((l * NHn + n) * HDd) * HDd + e;
#pragma unroll
        for (int d = 0; d < HDd; ++d) {
            rI[d] = Ri[rb + d * HDd]; rF[d] = Rf[rb + d * HDd];
            rZ[d] = Rz[rb + d * HDd]; rO[d] = Ro[rb + d * HDd];
        }
    }
    float bI = bi[l * Hh + jj], bF = bf[l * Hh + jj];
    float bZ = bz[l * Hh + jj], bO = bo[l * Hh + jj];

    // ---- projection weights (used by wave 1; loaded by all, clamped) ----
    const int p  = (j >= 64) ? (j - 64) : j;   // lane within wave 1
    const int d8 = p & 7, ch = p >> 3;
    float wp_r[16];
    {
        const int base = l * Dd * Hh + d8 * Hh + ch * HDd;
#pragma unroll
        for (int k = 0; k < HDd; ++k) wp_r[k] = Wp[base + k];
        wp_r[15] = 0.f;   // pairs with hb pad element (always 0)
    }
    float bp_r = bp[l * Dd + d8];

    float cst = 0.f, nst = 0.f, mst = 0.f;

    __syncthreads();

    // ---- pipelined recurrence: ONE barrier per tick ----
    for (int tau = 0; tau < T + 2 * Ll - 1; ++tau) {
        const int t_g = tau - 2 * l;       // gate timestep
        const int t_p = t_g - 1;           // projection timestep

        // gates: read xs[t_g] + h(t_g-1), write h(t_g)
        if (gl && (t_g >= 0) && (t_g < T)) {
            const float4* xt4 = (const float4*)(xs + t_g * Dd);
            const float4 xa = xt4[0], xb2 = xt4[1];
            const float xv[Dd] = {xa.x, xa.y, xa.z, xa.w, xb2.x, xb2.y, xb2.z, xb2.w};
            float gi = bI, gf = bF, gz = bZ, go = bO;
#pragma unroll
            for (int d = 0; d < Dd; ++d) {
                gi = fmaf(xv[d], wI[d], gi);
                gf = fmaf(xv[d], wF[d], gf);
                gz = fmaf(xv[d], wZ[d], gz);
                go = fmaf(xv[d], wO[d], go);
            }
            const float4* h4 = (const float4*)(&hb[l][t_g & 1][n * HP]);
            const float4 h0 = h4[0], h1 = h4[1], h2 = h4[2], h3 = h4[3];
            const float hv[16] = {h0.x, h0.y, h0.z, h0.w, h1.x, h1.y, h1.z, h1.w,
                                  h2.x, h2.y, h2.z, h2.w, h3.x, h3.y, h3.z, h3.w};
#pragma unroll
            for (int d = 0; d < HDd; ++d) {
                gi = fmaf(hv[d], rI[d], gi);
                gf = fmaf(hv[d], rF[d], gf);
                gz = fmaf(hv[d], rZ[d], gz);
                go = fmaf(hv[d], rO[d], go);
            }
            const float z  = tanh_fast(gz);
            const float o  = sigm_fast(go);
            const float mn = fmaxf(gf + mst, gi);
            const float ip = __expf(gi - mn);
            const float fp = __expf(gf + mst - mn);
            cst = fmaf(fp, cst, ip * z);
            nst = fmaf(fp, nst, ip);
            mst = mn;
            hb[l][(t_g & 1) ^ 1][n * HP + e] = o * cst * fast_rcp(nst);
        }

        // projection of h(t_p) (wave 1 of the group), residual into xs[t_p]
        if ((j >= 64) && (t_p >= 0) && (t_p < T)) {
            // h(t_p) lives in buffer (t_p&1)^1 == t_g&1
            const float4* h4 = (const float4*)(&hb[l][t_g & 1][ch * HP]);
            const float4 h0 = h4[0], h1 = h4[1], h2 = h4[2], h3 = h4[3];
            const float hv[16] = {h0.x, h0.y, h0.z, h0.w, h1.x, h1.y, h1.z, h1.w,
                                  h2.x, h2.y, h2.z, h2.w, h3.x, h3.y, h3.z, h3.w};
            float s = 0.f;
#pragma unroll
            for (int k = 0; k < 16; ++k) s = fmaf(hv[k], wp_r[k], s);
            s += __shfl_xor(s, 8);
            s += __shfl_xor(s, 16);
            s += __shfl_xor(s, 32);
            if (p < Dd) xs[t_p * Dd + p] += s + bp_r;   // residual update
        }

        __syncthreads();
    }

    if (tid < Dd) last_out[b * Dd + tid] = xs[(T - 1) * Dd + tid];
}

// One block of Bsz threads: batch-norm over batch + FC + sigmoid.
// Mean/var parallelized: 32 groups x 8 dims partials, then 8-lane combine.
__global__ __launch_bounds__(Bsz) void bn_fc_kernel(
    const float* __restrict__ last,   // [Bsz][Dd]
    const float* __restrict__ gamma, const float* __restrict__ beta,
    const float* __restrict__ Wfc,   const float* __restrict__ bfc,
    float* __restrict__ out)          // [Bsz]
{
    __shared__ __align__(16) float ls[Bsz][Dd];
    __shared__ float rsum[32][Dd], rsq[32][Dd];
    __shared__ float mu[Dd], rstdg[Dd], bet[Dd], wfc[Dd];
    const int tid = threadIdx.x;
    {
        const float4* lg = (const float4*)last;
        ((float4*)ls)[tid]       = lg[tid];        // 256*8 floats = 512 float4
        ((float4*)ls)[tid + 256] = lg[tid + 256];
    }
    __syncthreads();
    {
        const int d = tid & 7, g = tid >> 3;       // 32 groups x 8 dims
        float s = 0.f, q = 0.f;
#pragma unroll
        for (int k = 0; k < 8; ++k) {
            const float v = ls[g + 32 * k][d];
            s += v; q = fmaf(v, v, q);
        }
        rsum[g][d] = s; rsq[g][d] = q;
    }
    __syncthreads();
    if (tid < Dd) {
        float s = 0.f, q = 0.f;
#pragma unroll
        for (int g = 0; g < 32; ++g) { s += rsum[g][tid]; q += rsq[g][tid]; }
        const float mean = s * (1.f / Bsz);
        const float var  = q * (1.f / Bsz) - mean * mean;
        mu[tid]    = mean;
        rstdg[tid] = rsqrtf(fmaxf(var, 0.f) + EPSf) * gamma[tid];
        bet[tid]   = beta[tid];
        wfc[tid]   = Wfc[tid];
    }
    __syncthreads();
    float acc = bfc[0];
#pragma unroll
    for (int d = 0; d < Dd; ++d)
        acc += ((ls[tid][d] - mu[d]) * rstdg[d] + bet[d]) * wfc[d];
    out[tid] = sigm_fast(acc);
}

extern "C" void kernel_launch(void* const* d_in, const int* in_sizes, int n_in,
                              void* d_out, int out_size, void* d_ws, size_t ws_size,
                              hipStream_t stream) {
    const float* x    = (const float*)d_in[0];
    const float* Wi   = (const float*)d_in[1];
    const float* Wf   = (const float*)d_in[2];
    const float* Wz   = (const float*)d_in[3];
    const float* Wo   = (const float*)d_in[4];
    const float* Ri   = (const float*)d_in[5];
    const float* Rf   = (const float*)d_in[6];
    const float* Rz   = (const float*)d_in[7];
    const float* Ro   = (const float*)d_in[8];
    const float* bi   = (const float*)d_in[9];
    const float* bf   = (const float*)d_in[10];
    const float* bz   = (const float*)d_in[11];
    const float* bo   = (const float*)d_in[12];
    const float* Wp   = (const float*)d_in[13];
    const float* bp   = (const float*)d_in[14];
    const float* gamma= (const float*)d_in[15];
    const float* beta = (const float*)d_in[16];
    const float* Wfc  = (const float*)d_in[17];
    const float* bfc  = (const float*)d_in[18];

    float* last_ws = (float*)d_ws;          // Bsz*Dd floats
    float* out     = (float*)d_out;         // Bsz floats

    slstm_kernel<<<Bsz, 512, 0, stream>>>(x, Wi, Wf, Wz, Wo, Ri, Rf, Rz, Ro,
                                          bi, bf, bz, bo, Wp, bp, last_ws);
    bn_fc_kernel<<<1, Bsz, 0, stream>>>(last_ws, gamma, beta, Wfc, bfc, out);
}